// Round 19
// baseline (205.184 us; speedup 1.0000x reference)
//
#include <hip/hip_runtime.h>
#include <hip/hip_bf16.h>
#include <stdint.h>

#define B_ 4
#define T_ 2048
#define D_ 1024
#define H_ 16
#define M_ (B_*T_)    // 8192
#define N1_ (3*D_)    // 3072

typedef __attribute__((ext_vector_type(8))) short short8;
typedef __attribute__((ext_vector_type(4))) short short4v;
typedef __attribute__((ext_vector_type(4))) float f32x4;
typedef __attribute__((ext_vector_type(16))) float f32x16;

typedef const __attribute__((address_space(1))) void* as1cp;
typedef __attribute__((address_space(3))) void* as3p;

__device__ __forceinline__ ushort f2bf(float f) {
  union { float f; unsigned u; } v; v.f = f;
  unsigned r = v.u + 0x7fffu + ((v.u >> 16) & 1u);
  return (ushort)(r >> 16);
}

__device__ __forceinline__ float fast_exp2(float x) {
#if __has_builtin(__builtin_amdgcn_exp2f)
  return __builtin_amdgcn_exp2f(x);
#else
  float r;
  asm("v_exp_f32 %0, %1" : "=v"(r) : "v"(x));
  return r;
#endif
}

// merged cast: x, Wqkv, Wout in one launch (all memory-bound)
__global__ void cast3_f32_bf16(const float* __restrict__ a, ushort* __restrict__ oa, int na,
                               const float* __restrict__ b, ushort* __restrict__ ob, int nb,
                               const float* __restrict__ c, ushort* __restrict__ oc, int nc) {
  int i = blockIdx.x * blockDim.x + threadIdx.x;
  int stride = gridDim.x * blockDim.x;
  int ntot = na + nb + nc;
  for (; i < ntot; i += stride) {
    const float* src; ushort* dst; int j = i;
    if (j < na) { src = a; dst = oa; }
    else if ((j -= na) < nb) { src = b; dst = ob; }
    else { j -= nb; src = c; dst = oc; }
    float4 v = reinterpret_cast<const float4*>(src)[j];
    ushort4 o;
    o.x = f2bf(v.x); o.y = f2bf(v.y); o.z = f2bf(v.z); o.w = f2bf(v.w);
    reinterpret_cast<ushort4*>(dst)[j] = o;
  }
}

__device__ __forceinline__ void gload_lds16(const ushort* g, ushort* l) {
  __builtin_amdgcn_global_load_lds((as1cp)(const void*)g, (as3p)(void*)l, 16, 0, 0);
}

__device__ __forceinline__ short4v ds_tr16(unsigned addr) {
  short4v r;
  asm volatile("ds_read_b64_tr_b16 %0, %1" : "=v"(r) : "v"(addr) : "memory");
  return r;
}

__device__ __forceinline__ short8 cat8(short4v a, short4v b) {
  short8 r;
  r[0]=a[0]; r[1]=a[1]; r[2]=a[2]; r[3]=a[3];
  r[4]=b[0]; r[5]=b[1]; r[6]=b[2]; r[7]=b[3];
  return r;
}

__device__ __forceinline__ unsigned cvtpk(float lo, float hi) {
  unsigned r;
  asm("v_cvt_pk_bf16_f32 %0, %1, %2" : "=v"(r) : "v"(lo), "v"(hi));
  return r;
}

__device__ __forceinline__ f32x16 mfma32(short8 a, short8 b, f32x16 c) {
  return __builtin_amdgcn_mfma_f32_32x32x16_bf16(a, b, c, 0, 0, 0);
}

// ---------------- GEMM 128x256, wave tile 64x128, double-buffered, swizzled ----------------
// 4 waves (256 thr). Wave (wr,wc) in 2x2 owns 64 rows x 128 cols -> 32 MFMA per
// 32-K tile off 12 ds_read_b128 (0.375 reads/MFMA vs 0.5). Double-buffer with
// attn9-proven ledger: at top of t issue t+1's 6 loads, vmcnt(6) drains t's.
// Both-sides XOR chunk swizzle (r17-proven: coalesced global + 2-way LDS banks).
// MODE: 0 = f32 out, 1 = bf16 out, 2 = bf16 out with q-scale on cols<1024
template<int MODE>
__global__ __launch_bounds__(256) void gemm_w2(const ushort* __restrict__ A,
                                               const ushort* __restrict__ Bm,
                                               void* __restrict__ Cout,
                                               int M, int N, int K, int gx) {
  __shared__ ushort Al[2][4096];   // 2 x 8KB  (128 rows x 32 k)
  __shared__ ushort Bl[2][8192];   // 2 x 16KB (256 rows x 32 k)
  const int tid  = threadIdx.x;
  const int lane = tid & 63;
  const int w    = tid >> 6;       // 0..3
  const int g    = lane >> 4;
  const int ln   = lane & 15;

  const int nwg = gridDim.x;
  const int cpx = nwg >> 3;
  const int id  = (int)blockIdx.x;
  const int swz = (id & 7) * cpx + (id >> 3);
  const int m0 = (swz / gx) * 128;
  const int n0 = (swz % gx) * 256;
  const int wr = w >> 1, wc = w & 1;

  // staging: chunk idx -> row=idx>>2, in-row 16B slot (idx&3) XOR'd by (idx>>3)&3.
  // A: idx = j*256+tid (j=0..1, 512 chunks). B: idx = j*256+tid (j=0..3, 1024 chunks).
  int arow[2], acb[2];
  #pragma unroll
  for (int j = 0; j < 2; ++j) {
    int idx = j*256 + tid;
    arow[j] = idx >> 2;
    acb[j]  = ((idx & 3) * 16) ^ (((idx >> 3) & 3) << 4);
  }
  int brow[4], bcb[4];
  #pragma unroll
  for (int j = 0; j < 4; ++j) {
    int idx = j*256 + tid;
    brow[j] = idx >> 2;
    bcb[j]  = ((idx & 3) * 16) ^ (((idx >> 3) & 3) << 4);
  }

  auto STAGE = [&](int slot, int kt) {
    #pragma unroll
    for (int j = 0; j < 2; ++j)
      gload_lds16(A + (size_t)(m0 + arow[j]) * K + kt + (acb[j] >> 1),
                  &Al[slot][(j*4 + w) * 512]);
    #pragma unroll
    for (int j = 0; j < 4; ++j)
      gload_lds16(Bm + (size_t)(n0 + brow[j]) * K + kt + (bcb[j] >> 1),
                  &Bl[slot][(j*4 + w) * 512]);
  };

  const int NT = K >> 5;
  f32x4 acc[4][8] = {};

  STAGE(0, 0);

  const int rx = ((ln >> 1) & 3) << 3;   // read-side XOR (ushort units)

  for (int t = 0; t < NT; ++t) {
    const int slot = t & 1;
    if (t + 1 < NT) {
      STAGE(slot ^ 1, (t + 1) * 32);
      asm volatile("s_waitcnt vmcnt(6)" ::: "memory");
    } else {
      asm volatile("s_waitcnt vmcnt(0)" ::: "memory");
    }
    asm volatile("s_barrier" ::: "memory");

    short8 a[4], b[8];
    #pragma unroll
    for (int m = 0; m < 4; ++m)
      a[m] = *(const short8*)&Al[slot][(wr*64 + m*16 + ln) * 32 + ((g*8) ^ rx)];
    #pragma unroll
    for (int n = 0; n < 8; ++n)
      b[n] = *(const short8*)&Bl[slot][(wc*128 + n*16 + ln) * 32 + ((g*8) ^ rx)];
    __builtin_amdgcn_s_setprio(1);
    #pragma unroll
    for (int m = 0; m < 4; ++m)
      #pragma unroll
      for (int n = 0; n < 8; ++n)
        acc[m][n] = __builtin_amdgcn_mfma_f32_16x16x32_bf16(a[m], b[n], acc[m][n], 0, 0, 0);
    __builtin_amdgcn_s_setprio(0);
    asm volatile("s_barrier" ::: "memory");
  }

  #pragma unroll
  for (int m = 0; m < 4; ++m) {
    int gr = m0 + wr*64 + m*16 + g*4;
    #pragma unroll
    for (int n = 0; n < 8; ++n) {
      int gc = n0 + wc*128 + n*16 + ln;
      #pragma unroll
      for (int r = 0; r < 4; ++r) {
        float v = acc[m][n][r];
        if (MODE == 2 && gc < 1024) v *= 0.18033688011112042f;  // 0.125*log2(e)
        if (MODE) ((ushort*)Cout)[(size_t)(gr + r) * N + gc] = f2bf(v);
        else      ((float*)Cout)[(size_t)(gr + r) * N + gc]  = v;
      }
    }
  }
}

// ---------------- Flash attention v11 (proven; unchanged) ----------------
__global__ __launch_bounds__(512, 2) void attn11(const ushort* __restrict__ qkv,
                                                 ushort* __restrict__ y) {
  __shared__ ushort Kl[2][8192];
  __shared__ ushort Vl[2][8192];

  const int tid  = threadIdx.x;
  const int lane = tid & 63;
  const int w    = tid >> 6;
  const int l31  = lane & 31;
  const int hi   = lane >> 5;

  const int bh = blockIdx.x;
  const int b  = bh >> 4;
  const int h  = bh & 15;
  const int qb = 7 - (int)blockIdx.y;
  const int rowg = b * T_;
  const int q0 = qb * 256;
  const int qw = q0 + w * 32;
  const int qrow = qw + l31;
  const int nt = 2 * qb + 2;

  const int krow0 = tid >> 3;
  const int kcb   = ((tid & 7) * 16) ^ ((krow0 & 7) << 4);
  const int vdh = tid & 1, vr = (tid >> 1) & 3, vg = (tid >> 3) & 3,
            vkq = (tid >> 5) & 1, vks = (tid >> 6) & 7;
  const int vkey = vks*16 + vkq*8 + (vg >> 1)*4 + vr;
  const int vdd  = (vg & 1)*16 + vdh*8;

  short8 qf[4];
  {
    const ushort* qp = qkv + (size_t)(rowg + qrow) * N1_ + h*64 + hi*8;
    #pragma unroll
    for (int kc = 0; kc < 4; ++kc) qf[kc] = *(const short8*)(qp + kc*16);
  }

  f32x16 oacc[2] = {};
  float lrun = 0.f;

  const unsigned VbBase = (unsigned)(size_t)(as3p)(void*)&Vl[0][0];
  const unsigned trln = (unsigned)(((lane >> 4) * 128) + (lane & 15) * 8);

  auto STAGE = [&](int bufi, int kb) {
    const ushort* Ks = qkv + (size_t)(rowg + kb + krow0) * N1_ + D_ + h*64 + (kcb >> 1);
    gload_lds16(Ks,                     &Kl[bufi][tid*8]);
    gload_lds16(Ks + (size_t)64 * N1_,  &Kl[bufi][(512 + tid)*8]);
    const ushort* Vs = qkv + (size_t)(rowg + kb + vkey) * N1_ + 2*D_ + h*64 + vdd;
    gload_lds16(Vs,      &Vl[bufi][tid*8]);
    gload_lds16(Vs + 32, &Vl[bufi][(512 + tid)*8]);
  };

  STAGE(0, 0);

  for (int kt = 0; kt < nt; ++kt) {
    const int buf = kt & 1;
    const int kbase = kt * 128;
    if (kt + 1 < nt) {
      STAGE(buf ^ 1, kbase + 128);
      asm volatile("s_waitcnt vmcnt(4)" ::: "memory");
    } else {
      asm volatile("s_waitcnt vmcnt(0)" ::: "memory");
    }
    asm volatile("s_barrier" ::: "memory");

    #pragma unroll
    for (int h2 = 0; h2 < 2; ++h2) {
      const int kb2 = kbase + h2 * 64;
      if (kb2 <= qw + 31) {
        f32x16 sv[2] = {};
        const char* Kb = (const char*)&Kl[buf][0] + h2 * 8192;
        __builtin_amdgcn_s_setprio(1);
        #pragma unroll
        for (int kc = 0; kc < 4; ++kc) {
          unsigned co = (unsigned)((kc*32 + hi*16) ^ ((l31 & 7) << 4));
          short8 k0 = *(const short8*)(Kb + (size_t)l31*128 + co);
          short8 k1 = *(const short8*)(Kb + (size_t)(32 + l31)*128 + co);
          sv[0] = mfma32(k0, qf[kc], sv[0]);
          sv[1] = mfma32(k1, qf[kc], sv[1]);
        }
        __builtin_amdgcn_s_setprio(0);

        if (kb2 + 63 > qw) {
          #pragma unroll
          for (int t = 0; t < 2; ++t)
            #pragma unroll
            for (int r = 0; r < 16; ++r) {
              int kl = kb2 + t*32 + (r & 3) + 8*(r >> 2) + 4*hi;
              if (kl > qrow) sv[t][r] = -1.0e38f;
            }
        }

        #pragma unroll
        for (int t = 0; t < 2; ++t)
          #pragma unroll
          for (int r = 0; r < 16; ++r) sv[t][r] = fast_exp2(sv[t][r]);
        float ts[8];
        #pragma unroll
        for (int r = 0; r < 8; ++r)
          ts[r] = (sv[0][r] + sv[0][r+8]) + (sv[1][r] + sv[1][r+8]);
        lrun += ((ts[0] + ts[1]) + (ts[2] + ts[3])) + ((ts[4] + ts[5]) + (ts[6] + ts[7]));

        const unsigned Vb = VbBase + (unsigned)(buf * 16384);
        short4v vt[2][4][2];
        #pragma unroll
        for (int dt = 0; dt < 2; ++dt)
          #pragma unroll
          for (int ks = 0; ks < 4; ++ks) {
            unsigned a = Vb + (unsigned)(dt*8192 + (h2*4 + ks)*1024) + trln;
            vt[dt][ks][0] = ds_tr16(a);
            vt[dt][ks][1] = ds_tr16(a + 512);
          }

        short8 pa[4];
        #pragma unroll
        for (int ks = 0; ks < 4; ++ks) {
          const int t = ks >> 1, base = 8 * (ks & 1);
          union { unsigned u[4]; short8 v; } uu;
          uu.u[0] = cvtpk(sv[t][base+0], sv[t][base+1]);
          uu.u[1] = cvtpk(sv[t][base+2], sv[t][base+3]);
          uu.u[2] = cvtpk(sv[t][base+4], sv[t][base+5]);
          uu.u[3] = cvtpk(sv[t][base+6], sv[t][base+7]);
          pa[ks] = uu.v;
        }

        asm volatile("s_waitcnt lgkmcnt(0)" ::: "memory");
        __builtin_amdgcn_sched_barrier(0);
        __builtin_amdgcn_s_setprio(1);
        #pragma unroll
        for (int ks = 0; ks < 4; ++ks) {
          oacc[0] = mfma32(cat8(vt[0][ks][0], vt[0][ks][1]), pa[ks], oacc[0]);
          oacc[1] = mfma32(cat8(vt[1][ks][0], vt[1][ks][1]), pa[ks], oacc[1]);
        }
        __builtin_amdgcn_s_setprio(0);
      }
    }
    asm volatile("s_barrier" ::: "memory");
  }

  float ltot = lrun + __shfl_xor(lrun, 32);
  const float inv = 1.0f / ltot;
  #pragma unroll
  for (int dt = 0; dt < 2; ++dt) {
    #pragma unroll
    for (int rq = 0; rq < 4; ++rq) {
      ushort4 pk4;
      pk4.x = f2bf(oacc[dt][rq*4+0] * inv);
      pk4.y = f2bf(oacc[dt][rq*4+1] * inv);
      pk4.z = f2bf(oacc[dt][rq*4+2] * inv);
      pk4.w = f2bf(oacc[dt][rq*4+3] * inv);
      *(ushort4*)&y[(size_t)(rowg + qrow) * D_ + h*64 + dt*32 + rq*8 + hi*4] = pk4;
    }
  }
}

extern "C" void kernel_launch(void* const* d_in, const int* in_sizes, int n_in,
                              void* d_out, int out_size, void* d_ws, size_t ws_size,
                              hipStream_t stream) {
  const float* x    = (const float*)d_in[0];
  const float* Wqkv = (const float*)d_in[1];
  const float* Wout = (const float*)d_in[2];

  ushort* xb    = (ushort*)d_ws;
  ushort* wqkvb = xb    + (size_t)M_ * D_;
  ushort* woutb = wqkvb + (size_t)N1_ * D_;
  ushort* qkvb  = woutb + (size_t)D_ * D_;
  ushort* yb    = qkvb  + (size_t)M_ * N1_;

  cast3_f32_bf16<<<2048, 256, 0, stream>>>(x, xb, M_ * D_ / 4,
                                           Wqkv, wqkvb, N1_ * D_ / 4,
                                           Wout, woutb, D_ * D_ / 4);

  // GEMM1: 128x256 wave-64x128 (grid 64x12 = 768, %8==0)
  gemm_w2<2><<<(M_/128)*(N1_/256), 256, 0, stream>>>(xb, wqkvb, qkvb, M_, N1_, D_, N1_/256);

  attn11<<<dim3(B_*H_, 8), 512, 0, stream>>>(qkvb, yb);

  // GEMM2: 128x256 wave-64x128 (grid 64x4 = 256, %8==0)
  gemm_w2<0><<<(M_/128)*(D_/256), 256, 0, stream>>>(yb, woutb, d_out, M_, D_, D_, D_/256);
}

// Round 20
// 157.449 us; speedup vs baseline: 1.3032x; 1.3032x over previous
//
#include <hip/hip_runtime.h>
#include <hip/hip_bf16.h>
#include <stdint.h>

#define B_ 4
#define T_ 2048
#define D_ 1024
#define H_ 16
#define M_ (B_*T_)    // 8192
#define N1_ (3*D_)    // 3072

typedef __attribute__((ext_vector_type(8))) short short8;
typedef __attribute__((ext_vector_type(4))) short short4v;
typedef __attribute__((ext_vector_type(4))) float f32x4;
typedef __attribute__((ext_vector_type(16))) float f32x16;

typedef const __attribute__((address_space(1))) void* as1cp;
typedef __attribute__((address_space(3))) void* as3p;

__device__ __forceinline__ ushort f2bf(float f) {
  union { float f; unsigned u; } v; v.f = f;
  unsigned r = v.u + 0x7fffu + ((v.u >> 16) & 1u);
  return (ushort)(r >> 16);
}

__device__ __forceinline__ float fast_exp2(float x) {
#if __has_builtin(__builtin_amdgcn_exp2f)
  return __builtin_amdgcn_exp2f(x);
#else
  float r;
  asm("v_exp_f32 %0, %1" : "=v"(r) : "v"(x));
  return r;
#endif
}

// merged cast: x, Wqkv, Wout in one launch (all memory-bound)
__global__ void cast3_f32_bf16(const float* __restrict__ a, ushort* __restrict__ oa, int na,
                               const float* __restrict__ b, ushort* __restrict__ ob, int nb,
                               const float* __restrict__ c, ushort* __restrict__ oc, int nc) {
  int i = blockIdx.x * blockDim.x + threadIdx.x;
  int stride = gridDim.x * blockDim.x;
  int ntot = na + nb + nc;
  for (; i < ntot; i += stride) {
    const float* src; ushort* dst; int j = i;
    if (j < na) { src = a; dst = oa; }
    else if ((j -= na) < nb) { src = b; dst = ob; }
    else { j -= nb; src = c; dst = oc; }
    float4 v = reinterpret_cast<const float4*>(src)[j];
    ushort4 o;
    o.x = f2bf(v.x); o.y = f2bf(v.y); o.z = f2bf(v.z); o.w = f2bf(v.w);
    reinterpret_cast<ushort4*>(dst)[j] = o;
  }
}

__device__ __forceinline__ void gload_lds16(const ushort* g, ushort* l) {
  __builtin_amdgcn_global_load_lds((as1cp)(const void*)g, (as3p)(void*)l, 16, 0, 0);
}

__device__ __forceinline__ short4v ds_tr16(unsigned addr) {
  short4v r;
  asm volatile("ds_read_b64_tr_b16 %0, %1" : "=v"(r) : "v"(addr) : "memory");
  return r;
}

__device__ __forceinline__ short8 cat8(short4v a, short4v b) {
  short8 r;
  r[0]=a[0]; r[1]=a[1]; r[2]=a[2]; r[3]=a[3];
  r[4]=b[0]; r[5]=b[1]; r[6]=b[2]; r[7]=b[3];
  return r;
}

__device__ __forceinline__ unsigned cvtpk(float lo, float hi) {
  unsigned r;
  asm("v_cvt_pk_bf16_f32 %0, %1, %2" : "=v"(r) : "v"(lo), "v"(hi));
  return r;
}

__device__ __forceinline__ f32x16 mfma32(short8 a, short8 b, f32x16 c) {
  return __builtin_amdgcn_mfma_f32_32x32x16_bf16(a, b, c, 0, 0, 0);
}

// ---------------- GEMM 128² DOUBLE-buffered (32KB LDS -> 5 blocks/CU) ----------------
// attn11-proven rhythm: top of t = STAGE(t+1 into other slot) + vmcnt(4) + barrier;
// reads+MFMA; trailing barrier (WAR guard: t+1 stages into the slot t just read).
// Both-sides XOR chunk swizzle (r17-proven: coalesced global, 2-way LDS banks, 0 conflicts).
// MODE: 0 = f32 out, 1 = bf16 out, 2 = bf16 out with q-scale on cols<1024
template<int MODE>
__global__ __launch_bounds__(256) void gemm_db(const ushort* __restrict__ A,
                                               const ushort* __restrict__ Bm,
                                               void* __restrict__ Cout,
                                               int M, int N, int K, int gx) {
  __shared__ ushort Al[2][4096];   // 2 slots x 8KB
  __shared__ ushort Bl[2][4096];
  const int tid  = threadIdx.x;
  const int lane = tid & 63;
  const int w    = tid >> 6;
  const int g    = lane >> 4;
  const int ln   = lane & 15;

  const int nwg = gridDim.x;
  const int cpx = nwg >> 3;
  const int id  = (int)blockIdx.x;
  const int swz = (id & 7) * cpx + (id >> 3);
  const int m0 = (swz / gx) * 128;
  const int n0 = (swz % gx) * 128;
  const int wr = w >> 1, wc = w & 1;

  // staging coords (r17-proven): chunk idx -> row=idx>>2; in-row 16B slot XOR'd
  int srow[2], kcb[2], scc[2];
  #pragma unroll
  for (int j = 0; j < 2; ++j) {
    int cc  = w * 2 + j;
    int idx = cc * 64 + lane;
    scc[j]  = cc;
    srow[j] = idx >> 2;
    kcb[j]  = ((idx & 3) * 16) ^ (((idx >> 3) & 3) << 4);
  }

  auto STAGE = [&](int slot, int kt) {
    #pragma unroll
    for (int j = 0; j < 2; ++j) {
      gload_lds16(A  + (size_t)(m0 + srow[j]) * K + kt + (kcb[j] >> 1), &Al[slot][scc[j] * 512]);
      gload_lds16(Bm + (size_t)(n0 + srow[j]) * K + kt + (kcb[j] >> 1), &Bl[slot][scc[j] * 512]);
    }
  };

  const int NT = K >> 5;   // 32-wide K tiles
  f32x4 acc[4][4] = {};

  STAGE(0, 0);

  const int rx = ((ln >> 1) & 3) << 3;   // read-side XOR (ushort units)

  for (int t = 0; t < NT; ++t) {
    const int slot = t & 1;
    if (t + 1 < NT) {
      STAGE(slot ^ 1, (t + 1) * 32);
      asm volatile("s_waitcnt vmcnt(4)" ::: "memory");
    } else {
      asm volatile("s_waitcnt vmcnt(0)" ::: "memory");
    }
    asm volatile("s_barrier" ::: "memory");

    short8 a[4], b[4];
    #pragma unroll
    for (int m = 0; m < 4; ++m)
      a[m] = *(const short8*)&Al[slot][(wr*64 + m*16 + ln) * 32 + ((g*8) ^ rx)];
    #pragma unroll
    for (int n = 0; n < 4; ++n)
      b[n] = *(const short8*)&Bl[slot][(wc*64 + n*16 + ln) * 32 + ((g*8) ^ rx)];
    __builtin_amdgcn_s_setprio(1);
    #pragma unroll
    for (int m = 0; m < 4; ++m)
      #pragma unroll
      for (int n = 0; n < 4; ++n)
        acc[m][n] = __builtin_amdgcn_mfma_f32_16x16x32_bf16(a[m], b[n], acc[m][n], 0, 0, 0);
    __builtin_amdgcn_s_setprio(0);
    asm volatile("s_barrier" ::: "memory");   // WAR guard for next STAGE into this slot
  }

  #pragma unroll
  for (int m = 0; m < 4; ++m) {
    int gr = m0 + wr*64 + m*16 + g*4;
    #pragma unroll
    for (int n = 0; n < 4; ++n) {
      int gc = n0 + wc*64 + n*16 + ln;
      #pragma unroll
      for (int r = 0; r < 4; ++r) {
        float v = acc[m][n][r];
        if (MODE == 2 && gc < 1024) v *= 0.18033688011112042f;  // 0.125*log2(e)
        if (MODE) ((ushort*)Cout)[(size_t)(gr + r) * N + gc] = f2bf(v);
        else      ((float*)Cout)[(size_t)(gr + r) * N + gc]  = v;
      }
    }
  }
}

// ---------------- Flash attention v11 (proven; unchanged) ----------------
__global__ __launch_bounds__(512, 2) void attn11(const ushort* __restrict__ qkv,
                                                 ushort* __restrict__ y) {
  __shared__ ushort Kl[2][8192];
  __shared__ ushort Vl[2][8192];

  const int tid  = threadIdx.x;
  const int lane = tid & 63;
  const int w    = tid >> 6;
  const int l31  = lane & 31;
  const int hi   = lane >> 5;

  const int bh = blockIdx.x;
  const int b  = bh >> 4;
  const int h  = bh & 15;
  const int qb = 7 - (int)blockIdx.y;
  const int rowg = b * T_;
  const int q0 = qb * 256;
  const int qw = q0 + w * 32;
  const int qrow = qw + l31;
  const int nt = 2 * qb + 2;

  const int krow0 = tid >> 3;
  const int kcb   = ((tid & 7) * 16) ^ ((krow0 & 7) << 4);
  const int vdh = tid & 1, vr = (tid >> 1) & 3, vg = (tid >> 3) & 3,
            vkq = (tid >> 5) & 1, vks = (tid >> 6) & 7;
  const int vkey = vks*16 + vkq*8 + (vg >> 1)*4 + vr;
  const int vdd  = (vg & 1)*16 + vdh*8;

  short8 qf[4];
  {
    const ushort* qp = qkv + (size_t)(rowg + qrow) * N1_ + h*64 + hi*8;
    #pragma unroll
    for (int kc = 0; kc < 4; ++kc) qf[kc] = *(const short8*)(qp + kc*16);
  }

  f32x16 oacc[2] = {};
  float lrun = 0.f;

  const unsigned VbBase = (unsigned)(size_t)(as3p)(void*)&Vl[0][0];
  const unsigned trln = (unsigned)(((lane >> 4) * 128) + (lane & 15) * 8);

  auto STAGE = [&](int bufi, int kb) {
    const ushort* Ks = qkv + (size_t)(rowg + kb + krow0) * N1_ + D_ + h*64 + (kcb >> 1);
    gload_lds16(Ks,                     &Kl[bufi][tid*8]);
    gload_lds16(Ks + (size_t)64 * N1_,  &Kl[bufi][(512 + tid)*8]);
    const ushort* Vs = qkv + (size_t)(rowg + kb + vkey) * N1_ + 2*D_ + h*64 + vdd;
    gload_lds16(Vs,      &Vl[bufi][tid*8]);
    gload_lds16(Vs + 32, &Vl[bufi][(512 + tid)*8]);
  };

  STAGE(0, 0);

  for (int kt = 0; kt < nt; ++kt) {
    const int buf = kt & 1;
    const int kbase = kt * 128;
    if (kt + 1 < nt) {
      STAGE(buf ^ 1, kbase + 128);
      asm volatile("s_waitcnt vmcnt(4)" ::: "memory");
    } else {
      asm volatile("s_waitcnt vmcnt(0)" ::: "memory");
    }
    asm volatile("s_barrier" ::: "memory");

    #pragma unroll
    for (int h2 = 0; h2 < 2; ++h2) {
      const int kb2 = kbase + h2 * 64;
      if (kb2 <= qw + 31) {
        f32x16 sv[2] = {};
        const char* Kb = (const char*)&Kl[buf][0] + h2 * 8192;
        __builtin_amdgcn_s_setprio(1);
        #pragma unroll
        for (int kc = 0; kc < 4; ++kc) {
          unsigned co = (unsigned)((kc*32 + hi*16) ^ ((l31 & 7) << 4));
          short8 k0 = *(const short8*)(Kb + (size_t)l31*128 + co);
          short8 k1 = *(const short8*)(Kb + (size_t)(32 + l31)*128 + co);
          sv[0] = mfma32(k0, qf[kc], sv[0]);
          sv[1] = mfma32(k1, qf[kc], sv[1]);
        }
        __builtin_amdgcn_s_setprio(0);

        if (kb2 + 63 > qw) {
          #pragma unroll
          for (int t = 0; t < 2; ++t)
            #pragma unroll
            for (int r = 0; r < 16; ++r) {
              int kl = kb2 + t*32 + (r & 3) + 8*(r >> 2) + 4*hi;
              if (kl > qrow) sv[t][r] = -1.0e38f;
            }
        }

        #pragma unroll
        for (int t = 0; t < 2; ++t)
          #pragma unroll
          for (int r = 0; r < 16; ++r) sv[t][r] = fast_exp2(sv[t][r]);
        float ts[8];
        #pragma unroll
        for (int r = 0; r < 8; ++r)
          ts[r] = (sv[0][r] + sv[0][r+8]) + (sv[1][r] + sv[1][r+8]);
        lrun += ((ts[0] + ts[1]) + (ts[2] + ts[3])) + ((ts[4] + ts[5]) + (ts[6] + ts[7]));

        const unsigned Vb = VbBase + (unsigned)(buf * 16384);
        short4v vt[2][4][2];
        #pragma unroll
        for (int dt = 0; dt < 2; ++dt)
          #pragma unroll
          for (int ks = 0; ks < 4; ++ks) {
            unsigned a = Vb + (unsigned)(dt*8192 + (h2*4 + ks)*1024) + trln;
            vt[dt][ks][0] = ds_tr16(a);
            vt[dt][ks][1] = ds_tr16(a + 512);
          }

        short8 pa[4];
        #pragma unroll
        for (int ks = 0; ks < 4; ++ks) {
          const int t = ks >> 1, base = 8 * (ks & 1);
          union { unsigned u[4]; short8 v; } uu;
          uu.u[0] = cvtpk(sv[t][base+0], sv[t][base+1]);
          uu.u[1] = cvtpk(sv[t][base+2], sv[t][base+3]);
          uu.u[2] = cvtpk(sv[t][base+4], sv[t][base+5]);
          uu.u[3] = cvtpk(sv[t][base+6], sv[t][base+7]);
          pa[ks] = uu.v;
        }

        asm volatile("s_waitcnt lgkmcnt(0)" ::: "memory");
        __builtin_amdgcn_sched_barrier(0);
        __builtin_amdgcn_s_setprio(1);
        #pragma unroll
        for (int ks = 0; ks < 4; ++ks) {
          oacc[0] = mfma32(cat8(vt[0][ks][0], vt[0][ks][1]), pa[ks], oacc[0]);
          oacc[1] = mfma32(cat8(vt[1][ks][0], vt[1][ks][1]), pa[ks], oacc[1]);
        }
        __builtin_amdgcn_s_setprio(0);
      }
    }
    asm volatile("s_barrier" ::: "memory");
  }

  float ltot = lrun + __shfl_xor(lrun, 32);
  const float inv = 1.0f / ltot;
  #pragma unroll
  for (int dt = 0; dt < 2; ++dt) {
    #pragma unroll
    for (int rq = 0; rq < 4; ++rq) {
      ushort4 pk4;
      pk4.x = f2bf(oacc[dt][rq*4+0] * inv);
      pk4.y = f2bf(oacc[dt][rq*4+1] * inv);
      pk4.z = f2bf(oacc[dt][rq*4+2] * inv);
      pk4.w = f2bf(oacc[dt][rq*4+3] * inv);
      *(ushort4*)&y[(size_t)(rowg + qrow) * D_ + h*64 + dt*32 + rq*8 + hi*4] = pk4;
    }
  }
}

extern "C" void kernel_launch(void* const* d_in, const int* in_sizes, int n_in,
                              void* d_out, int out_size, void* d_ws, size_t ws_size,
                              hipStream_t stream) {
  const float* x    = (const float*)d_in[0];
  const float* Wqkv = (const float*)d_in[1];
  const float* Wout = (const float*)d_in[2];

  ushort* xb    = (ushort*)d_ws;
  ushort* wqkvb = xb    + (size_t)M_ * D_;
  ushort* woutb = wqkvb + (size_t)N1_ * D_;
  ushort* qkvb  = woutb + (size_t)D_ * D_;
  ushort* yb    = qkvb  + (size_t)M_ * N1_;

  cast3_f32_bf16<<<2048, 256, 0, stream>>>(x, xb, M_ * D_ / 4,
                                           Wqkv, wqkvb, N1_ * D_ / 4,
                                           Wout, woutb, D_ * D_ / 4);

  // GEMM1: double-buffered swizzled 128^2 (1536 blocks, %8==0; 5 blocks/CU)
  gemm_db<2><<<(N1_/128)*(M_/128), 256, 0, stream>>>(xb, wqkvb, qkvb, M_, N1_, D_, N1_/128);

  attn11<<<dim3(B_*H_, 8), 512, 0, stream>>>(qkvb, yb);

  // GEMM2: double-buffered swizzled 128^2 (512 blocks, %8==0)
  gemm_db<0><<<(D_/128)*(M_/128), 256, 0, stream>>>(yb, woutb, d_out, M_, D_, D_, D_/128);
}